// Round 8
// baseline (248.541 us; speedup 1.0000x reference)
//
#include <hip/hip_runtime.h>

#define L_SEQ 4096
#define DM 128
#define DIN 256
#define NC 128       // scan chunks
#define CHUNK 32     // L_SEQ / NC

// ---------------- K1: ConvTranspose2d(2x2,s2) + bias + concat -> seq (B,L,128)
__global__ __launch_bounds__(256) void upcat_kernel(
    const float* __restrict__ x, const float* __restrict__ skip,
    const float* __restrict__ up_w, const float* __restrict__ up_b,
    float* __restrict__ seq) {
  int b = blockIdx.x >> 6, hh = blockIdx.x & 63;
  int h = hh >> 1, i = hh & 1;
  int tid = threadIdx.x;
  __shared__ float xs[128][32];      // x[b][c][h][:]
  __shared__ float wsh[2][128][64];  // [j][c][o] for this i
  for (int e = tid; e < 1024; e += 256) {
    int c = e >> 3, q = e & 7;
    *(float4*)&xs[c][q * 4] =
        *(const float4*)(x + (((size_t)b * 128 + c) * 32 + h) * 32 + q * 4);
  }
  for (int e = tid; e < 8192; e += 256) {
    int c = e >> 6, o = e & 63;
    float2 v = *(const float2*)(up_w + c * 256 + o * 4 + i * 2);
    wsh[0][c][o] = v.x;
    wsh[1][c][o] = v.y;
  }
  __syncthreads();
  int tx = tid & 15, ty = tid >> 4;  // o-quad, ww-quad
  float4 bv = *(const float4*)(up_b + tx * 4);
  float acc[4][4];                   // [a -> ww=ty*4+a][o]
#pragma unroll
  for (int a = 0; a < 4; ++a) {
    acc[a][0] = bv.x; acc[a][1] = bv.y; acc[a][2] = bv.z; acc[a][3] = bv.w;
  }
#pragma unroll 4
  for (int c = 0; c < 128; ++c) {
    float x0 = xs[c][ty * 2];        // ww = 4ty+0,1  (w = 2ty)
    float x1 = xs[c][ty * 2 + 1];    // ww = 4ty+2,3  (w = 2ty+1)
    float4 w0 = *(const float4*)&wsh[0][c][tx * 4];
    float4 w1 = *(const float4*)&wsh[1][c][tx * 4];
    acc[0][0] = fmaf(x0, w0.x, acc[0][0]); acc[0][1] = fmaf(x0, w0.y, acc[0][1]);
    acc[0][2] = fmaf(x0, w0.z, acc[0][2]); acc[0][3] = fmaf(x0, w0.w, acc[0][3]);
    acc[1][0] = fmaf(x0, w1.x, acc[1][0]); acc[1][1] = fmaf(x0, w1.y, acc[1][1]);
    acc[1][2] = fmaf(x0, w1.z, acc[1][2]); acc[1][3] = fmaf(x0, w1.w, acc[1][3]);
    acc[2][0] = fmaf(x1, w0.x, acc[2][0]); acc[2][1] = fmaf(x1, w0.y, acc[2][1]);
    acc[2][2] = fmaf(x1, w0.z, acc[2][2]); acc[2][3] = fmaf(x1, w0.w, acc[2][3]);
    acc[3][0] = fmaf(x1, w1.x, acc[3][0]); acc[3][1] = fmaf(x1, w1.y, acc[3][1]);
    acc[3][2] = fmaf(x1, w1.z, acc[3][2]); acc[3][3] = fmaf(x1, w1.w, acc[3][3]);
  }
  size_t mrow_base = (size_t)b * L_SEQ + (size_t)hh * 64;
#pragma unroll
  for (int a = 0; a < 4; ++a) {
    int ww = ty * 4 + a;
    *(float4*)(seq + (mrow_base + ww) * DM + tx * 4) =
        make_float4(acc[a][0], acc[a][1], acc[a][2], acc[a][3]);
  }
  // skip half: channels 64..127
  for (int e = tid; e < 4096; e += 256) {
    int c = e & 63, ww = e >> 6;
    seq[(mrow_base + ww) * DM + 64 + c] =
        skip[((size_t)b * 64 + c) * (size_t)L_SEQ + hh * 64 + ww];
  }
}

// ---------------- generic fp32 GEMM: C[M][N] = A[M][K] @ W[N][K]^T
__global__ __launch_bounds__(256) void gemm_bt(
    const float* __restrict__ A, const float* __restrict__ W,
    float* __restrict__ C, int M, int N, int K) {
  __shared__ float As[32][68];  // [k][m], pad 68
  __shared__ float Ws[32][68];  // [k][n]
  int m0 = blockIdx.x * 64, n0 = blockIdx.y * 64;
  int tid = threadIdx.x;
  int tx = tid & 15, ty = tid >> 4;
  float acc[4][4];
#pragma unroll
  for (int a = 0; a < 4; ++a)
#pragma unroll
    for (int bb = 0; bb < 4; ++bb) acc[a][bb] = 0.f;

  for (int k0 = 0; k0 < K; k0 += 32) {
    __syncthreads();
    for (int e = tid; e < 512; e += 256) {
      int r = e >> 3;
      int c4 = (e & 7) << 2;
      float4 va = *(const float4*)(A + (size_t)(m0 + r) * K + k0 + c4);
      As[c4 + 0][r] = va.x; As[c4 + 1][r] = va.y;
      As[c4 + 2][r] = va.z; As[c4 + 3][r] = va.w;
      float4 vw = *(const float4*)(W + (size_t)(n0 + r) * K + k0 + c4);
      Ws[c4 + 0][r] = vw.x; Ws[c4 + 1][r] = vw.y;
      Ws[c4 + 2][r] = vw.z; Ws[c4 + 3][r] = vw.w;
    }
    __syncthreads();
#pragma unroll
    for (int kk = 0; kk < 32; ++kk) {
      float4 av = *(const float4*)(&As[kk][ty * 4]);
      float4 wv = *(const float4*)(&Ws[kk][tx * 4]);
      float av_[4] = {av.x, av.y, av.z, av.w};
      float wv_[4] = {wv.x, wv.y, wv.z, wv.w};
#pragma unroll
      for (int a = 0; a < 4; ++a)
#pragma unroll
        for (int bb = 0; bb < 4; ++bb)
          acc[a][bb] = fmaf(av_[a], wv_[bb], acc[a][bb]);
    }
  }
#pragma unroll
  for (int a = 0; a < 4; ++a)
#pragma unroll
    for (int bb = 0; bb < 4; ++bb)
      C[(size_t)(m0 + ty * 4 + a) * N + n0 + tx * 4 + bb] = acc[a][bb];
}

// ---------------- K3: depthwise causal conv1d + bias + silu -> u (B,L,256)
__global__ __launch_bounds__(256) void conv_silu_kernel(
    const float* __restrict__ xz, const float* __restrict__ cw,
    const float* __restrict__ cb, float* __restrict__ u) {
  int idx = blockIdx.x * 256 + threadIdx.x;   // over B*L*256
  int d = idx & 255;
  int m = idx >> 8;
  int l = m & (L_SEQ - 1);
  float acc = cb[d];
#pragma unroll
  for (int t = 0; t < 4; ++t) {
    int ls = l - 3 + t;
    if (ls >= 0)
      acc = fmaf(xz[(size_t)(m - 3 + t) * 512 + d], cw[d * 4 + t], acc);
  }
  u[idx] = acc / (1.f + __expf(-acc));
}

// ---------------- K4a: dbc = u @ x_proj_w^T  (M=16384, N=40, K=256)
__global__ __launch_bounds__(256) void xproj_kernel(
    const float* __restrict__ u, const float* __restrict__ W,
    float* __restrict__ dbc) {
  __shared__ float us[64][68];   // 64 rows x 64-k chunk, pad 68
  int m0 = blockIdx.x * 64;
  int tid = threadIdx.x;
  int lane = tid & 63;
  int w = __builtin_amdgcn_readfirstlane(tid >> 6);  // wave-uniform 0..3
  const float* Wb = W + w * 10 * 256;
  float acc[10];
#pragma unroll
  for (int j = 0; j < 10; ++j) acc[j] = 0.f;
  for (int k0 = 0; k0 < 256; k0 += 64) {
    __syncthreads();
    for (int e = tid; e < 1024; e += 256) {
      int r = e >> 4, q = e & 15;
      float4 v = *(const float4*)(u + (size_t)(m0 + r) * 256 + k0 + q * 4);
      *(float4*)&us[r][q * 4] = v;
    }
    __syncthreads();
#pragma unroll
    for (int kk = 0; kk < 64; kk += 4) {
      float4 a4 = *(const float4*)&us[lane][kk];
      float a_[4] = {a4.x, a4.y, a4.z, a4.w};
#pragma unroll
      for (int i = 0; i < 4; ++i)
#pragma unroll
        for (int j = 0; j < 10; ++j)
          acc[j] = fmaf(a_[i], Wb[j * 256 + k0 + kk + i], acc[j]);
    }
  }
  size_t base = (size_t)(m0 + lane) * 40 + w * 10;
#pragma unroll
  for (int j = 0; j < 10; ++j) dbc[base + j] = acc[j];
}

// ---------------- K5: chunked parallel selective scan ----------------
// thread = (b, chunk, d); 16 n-states in registers. Per-chunk dbc rows staged
// in LDS (broadcast reads); u/z register-prefetched (one vmcnt wait per chunk
// instead of per-timestep) -> latency off the recurrence critical path.

__device__ __forceinline__ float softplus_f(float a) {
  return (a > 20.f) ? a : log1pf(__expf(a));
}

__global__ __launch_bounds__(256) void scan_pass1(
    const float* __restrict__ u, const float* __restrict__ dbc,
    const float* __restrict__ A_log, const float* __restrict__ Wdt,
    const float* __restrict__ bdt, float* __restrict__ carryA,
    float* __restrict__ carryH) {
  int bid = blockIdx.x;          // b*NC + c
  int b = bid >> 7;
  int c = bid & (NC - 1);
  int d = threadIdx.x;
  __shared__ float ls[CHUNK * 40];
  size_t l0 = (size_t)b * L_SEQ + (size_t)c * CHUNK;
  const float* rp = dbc + l0 * 40;
  for (int e = d; e < CHUNK * 40; e += 256) ls[e] = rp[e];
  float Ac[16];
  {
    const float4* ar = (const float4*)(A_log + d * 16);
#pragma unroll
    for (int q = 0; q < 4; ++q) {
      float4 v = ar[q];
      Ac[q * 4 + 0] = -__expf(v.x); Ac[q * 4 + 1] = -__expf(v.y);
      Ac[q * 4 + 2] = -__expf(v.z); Ac[q * 4 + 3] = -__expf(v.w);
    }
  }
  float wdt[8];
  {
    const float4* wr = (const float4*)(Wdt + d * 8);
    float4 v0 = wr[0], v1 = wr[1];
    wdt[0] = v0.x; wdt[1] = v0.y; wdt[2] = v0.z; wdt[3] = v0.w;
    wdt[4] = v1.x; wdt[5] = v1.y; wdt[6] = v1.z; wdt[7] = v1.w;
  }
  float bdt_v = bdt[d];
  float ur[CHUNK];
  const float* up = u + l0 * 256 + d;
#pragma unroll
  for (int li = 0; li < CHUNK; ++li) ur[li] = up[(size_t)li * 256];
  __syncthreads();
  float h[16];
#pragma unroll
  for (int n = 0; n < 16; ++n) h[n] = 0.f;
  float dvs = 0.f;
#pragma unroll
  for (int li = 0; li < CHUNK; ++li) {
    float acc = bdt_v;
#pragma unroll
    for (int j = 0; j < 8; ++j)
      acc = fmaf(ls[li * 40 + j], wdt[j], acc);
    float dv = softplus_f(acc);
    dvs += dv;
    float t = dv * ur[li];
#pragma unroll
    for (int n = 0; n < 16; ++n) {
      float dA = __expf(dv * Ac[n]);
      h[n] = fmaf(dA, h[n], t * ls[li * 40 + 8 + n]);
    }
  }
  float4* cA = (float4*)(carryA + ((size_t)bid * 256 + d) * 16);
  float4* cH = (float4*)(carryH + ((size_t)bid * 256 + d) * 16);
#pragma unroll
  for (int q = 0; q < 4; ++q) {
    // prod of dA over chunk == exp(sum(dv) * Ac)
    cA[q] = make_float4(__expf(dvs * Ac[q * 4]), __expf(dvs * Ac[q * 4 + 1]),
                        __expf(dvs * Ac[q * 4 + 2]), __expf(dvs * Ac[q * 4 + 3]));
    cH[q] = make_float4(h[q * 4], h[q * 4 + 1], h[q * 4 + 2], h[q * 4 + 3]);
  }
}

__global__ __launch_bounds__(256) void scan_mid(
    const float* __restrict__ carryA, float* __restrict__ carryH) {
  int gid = blockIdx.x * 256 + threadIdx.x;  // 16384 chains
  int b = gid >> 12;
  int dn = gid & 4095;
  float h = 0.f;
  for (int c = 0; c < NC; ++c) {
    size_t i = ((size_t)(b * NC + c) << 12) + dn;
    float a = carryA[i];
    float hl = carryH[i];
    carryH[i] = h;                 // h entering chunk c
    h = fmaf(a, h, hl);
  }
}

__global__ __launch_bounds__(256) void scan_pass3(
    const float* __restrict__ u, const float* __restrict__ dbc,
    const float* __restrict__ xz, const float* __restrict__ A_log,
    const float* __restrict__ Wdt, const float* __restrict__ bdt,
    const float* __restrict__ Dp, const float* __restrict__ carryH,
    float* __restrict__ y) {
  int bid = blockIdx.x;
  int b = bid >> 7;
  int c = bid & (NC - 1);
  int d = threadIdx.x;
  __shared__ float ls[CHUNK * 40];
  size_t l0 = (size_t)b * L_SEQ + (size_t)c * CHUNK;
  const float* rp = dbc + l0 * 40;
  for (int e = d; e < CHUNK * 40; e += 256) ls[e] = rp[e];
  float Ac[16];
  {
    const float4* ar = (const float4*)(A_log + d * 16);
#pragma unroll
    for (int q = 0; q < 4; ++q) {
      float4 v = ar[q];
      Ac[q * 4 + 0] = -__expf(v.x); Ac[q * 4 + 1] = -__expf(v.y);
      Ac[q * 4 + 2] = -__expf(v.z); Ac[q * 4 + 3] = -__expf(v.w);
    }
  }
  float wdt[8];
  {
    const float4* wr = (const float4*)(Wdt + d * 8);
    float4 v0 = wr[0], v1 = wr[1];
    wdt[0] = v0.x; wdt[1] = v0.y; wdt[2] = v0.z; wdt[3] = v0.w;
    wdt[4] = v1.x; wdt[5] = v1.y; wdt[6] = v1.z; wdt[7] = v1.w;
  }
  float bdt_v = bdt[d];
  float Dv = Dp[d];
  float ur[CHUNK], zr[CHUNK];
  const float* up = u + l0 * 256 + d;
  const float* zp = xz + l0 * 512 + 256 + d;
#pragma unroll
  for (int li = 0; li < CHUNK; ++li) ur[li] = up[(size_t)li * 256];
#pragma unroll
  for (int li = 0; li < CHUNK; ++li) zr[li] = zp[(size_t)li * 512];
  float h[16];
  {
    const float4* cH = (const float4*)(carryH + ((size_t)bid * 256 + d) * 16);
#pragma unroll
    for (int q = 0; q < 4; ++q) {
      float4 v = cH[q];
      h[q * 4 + 0] = v.x; h[q * 4 + 1] = v.y;
      h[q * 4 + 2] = v.z; h[q * 4 + 3] = v.w;
    }
  }
  __syncthreads();
  float* yp = y + l0 * 256 + d;
#pragma unroll
  for (int li = 0; li < CHUNK; ++li) {
    float acc = bdt_v;
#pragma unroll
    for (int j = 0; j < 8; ++j)
      acc = fmaf(ls[li * 40 + j], wdt[j], acc);
    float dv = softplus_f(acc);
    float uv = ur[li];
    float zv = zr[li];
    float t = dv * uv;
    float p = 0.f;
#pragma unroll
    for (int n = 0; n < 16; ++n) {
      float dA = __expf(dv * Ac[n]);
      h[n] = fmaf(dA, h[n], t * ls[li * 40 + 8 + n]);
      p = fmaf(h[n], ls[li * 40 + 24 + n], p);
    }
    float s = zv / (1.f + __expf(-zv));
    yp[(size_t)li * 256] = (p + uv * Dv) * s;
  }
}

// ---------------- K6: LayerNorm(ch) + silu + 1x1 conv -> out (B,64,H2,W2)
__global__ __launch_bounds__(256) void ln_out_kernel(
    const float* __restrict__ s2, const float* __restrict__ gamma,
    const float* __restrict__ beta, const float* __restrict__ Wo,
    const float* __restrict__ bo, float* __restrict__ out) {
  __shared__ float xt[64][129];
  __shared__ float mus[64], invs[64];
  int tid = threadIdx.x;
  int m0 = blockIdx.x * 64;
  // Phase A: coalesced tile load -> LDS
  for (int i = 0; i < 8; ++i) {
    int s = tid + i * 256;          // 2048 float4 slots
    int r = s >> 5, q = s & 31;
    float4 v = *(const float4*)(s2 + (size_t)(m0 + r) * 128 + q * 4);
    xt[r][q * 4 + 0] = v.x; xt[r][q * 4 + 1] = v.y;
    xt[r][q * 4 + 2] = v.z; xt[r][q * 4 + 3] = v.w;
  }
  __syncthreads();
  // Phase B: stats, 4 threads per row
  {
    int r = tid >> 2, kq = (tid & 3) * 32;
    float s = 0.f, q = 0.f;
#pragma unroll 8
    for (int kk = 0; kk < 32; ++kk) {
      float v = xt[r][kq + kk];
      s += v; q = fmaf(v, v, q);
    }
    s += __shfl_xor(s, 1, 64); s += __shfl_xor(s, 2, 64);
    q += __shfl_xor(q, 1, 64); q += __shfl_xor(q, 2, 64);
    if ((tid & 3) == 0) {
      float mu = s * (1.f / 128.f);
      float var = q * (1.f / 128.f) - mu * mu;
      mus[r] = mu;
      invs[r] = rsqrtf(var + 1e-5f);
    }
  }
  __syncthreads();
  // Phase T: LN + silu in-place
  for (int i = 0; i < 32; ++i) {
    int idx = tid + i * 256;        // 8192 elements
    int r = idx >> 7, k = idx & 127;
    float v = xt[r][k];
    float xn = (v - mus[r]) * invs[r] * gamma[k] + beta[k];
    xt[r][k] = xn / (1.f + __expf(-xn));
  }
  __syncthreads();
  // Phase C: GEMM, lane = row, wave-uniform channels
  int lane = tid & 63;
  int w = __builtin_amdgcn_readfirstlane(tid >> 6);
  int cbase = blockIdx.y * 32 + w * 8;
  const float* Wrow = Wo + cbase * 128;
  float acc[8];
#pragma unroll
  for (int j = 0; j < 8; ++j) acc[j] = 0.f;
#pragma unroll 4
  for (int k = 0; k < 128; ++k) {
    float v = xt[lane][k];
#pragma unroll
    for (int j = 0; j < 8; ++j)
      acc[j] = fmaf(v, Wrow[j * 128 + k], acc[j]);
  }
  int m = m0 + lane;
  int b = m >> 12, l = m & 4095;
#pragma unroll
  for (int j = 0; j < 8; ++j)
    out[((size_t)b * 64 + cbase + j) * 4096 + l] = acc[j] + bo[cbase + j];
}

extern "C" void kernel_launch(void* const* d_in, const int* in_sizes, int n_in,
                              void* d_out, int out_size, void* d_ws, size_t ws_size,
                              hipStream_t stream) {
  (void)in_sizes; (void)n_in; (void)out_size; (void)ws_size;
  const float* x         = (const float*)d_in[0];
  const float* skip      = (const float*)d_in[1];
  const float* up_w      = (const float*)d_in[2];
  const float* up_b      = (const float*)d_in[3];
  const float* in_proj_w = (const float*)d_in[4];
  const float* conv1d_w  = (const float*)d_in[5];
  const float* conv1d_b  = (const float*)d_in[6];
  const float* x_proj_w  = (const float*)d_in[7];
  const float* dt_proj_w = (const float*)d_in[8];
  const float* dt_proj_b = (const float*)d_in[9];
  const float* A_log     = (const float*)d_in[10];
  const float* Dp        = (const float*)d_in[11];
  const float* out_proj_w= (const float*)d_in[12];
  const float* ln_gamma  = (const float*)d_in[13];
  const float* ln_beta   = (const float*)d_in[14];
  const float* convout_w = (const float*)d_in[15];
  const float* convout_b = (const float*)d_in[16];
  float* out = (float*)d_out;
  float* ws  = (float*)d_ws;

  // workspace layout (floats)
  float* seq    = ws;                  // 2,097,152  (reused as s2 after out_proj)
  float* xz     = ws + 2097152;        // 8,388,608
  float* u      = ws + 10485760;       // 4,194,304
  float* dbc    = ws + 14680064;       //   655,360
  float* y      = ws + 15335424;       // 4,194,304
  float* carryA = ws + 19529728;       // 2,097,152  (= 4*NC*256*16)
  float* carryH = ws + 21626880;       // 2,097,152

  upcat_kernel<<<256, 256, 0, stream>>>(x, skip, up_w, up_b, seq);
  gemm_bt<<<dim3(16384 / 64, 512 / 64), 256, 0, stream>>>(seq, in_proj_w, xz,
                                                          16384, 512, 128);
  conv_silu_kernel<<<16384, 256, 0, stream>>>(xz, conv1d_w, conv1d_b, u);
  xproj_kernel<<<16384 / 64, 256, 0, stream>>>(u, x_proj_w, dbc);
  scan_pass1<<<4 * NC, 256, 0, stream>>>(u, dbc, A_log, dt_proj_w, dt_proj_b,
                                         carryA, carryH);
  scan_mid<<<64, 256, 0, stream>>>(carryA, carryH);
  scan_pass3<<<4 * NC, 256, 0, stream>>>(u, dbc, xz, A_log, dt_proj_w,
                                         dt_proj_b, Dp, carryH, y);
  gemm_bt<<<dim3(16384 / 64, 128 / 64), 256, 0, stream>>>(y, out_proj_w, seq,
                                                          16384, 128, 256);
  ln_out_kernel<<<dim3(256, 2), 256, 0, stream>>>(seq, ln_gamma, ln_beta,
                                                  convout_w, convout_b, out);
}

// Round 9
// 217.451 us; speedup vs baseline: 1.1430x; 1.1430x over previous
//
#include <hip/hip_runtime.h>

#define L_SEQ 4096
#define DM 128
#define DIN 256
#define NC 128       // scan chunks
#define CHUNK 32     // L_SEQ / NC

// ---------------- K1: ConvTranspose2d(2x2,s2) + bias + concat -> seq (B,L,128)
__global__ __launch_bounds__(256) void upcat_kernel(
    const float* __restrict__ x, const float* __restrict__ skip,
    const float* __restrict__ up_w, const float* __restrict__ up_b,
    float* __restrict__ seq) {
  int b = blockIdx.x >> 6, hh = blockIdx.x & 63;
  int h = hh >> 1, i = hh & 1;
  int tid = threadIdx.x;
  __shared__ float xs[128][32];      // x[b][c][h][:]
  __shared__ float wsh[2][128][64];  // [j][c][o] for this i
  for (int e = tid; e < 1024; e += 256) {
    int c = e >> 3, q = e & 7;
    *(float4*)&xs[c][q * 4] =
        *(const float4*)(x + (((size_t)b * 128 + c) * 32 + h) * 32 + q * 4);
  }
  for (int e = tid; e < 8192; e += 256) {
    int c = e >> 6, o = e & 63;
    float2 v = *(const float2*)(up_w + c * 256 + o * 4 + i * 2);
    wsh[0][c][o] = v.x;
    wsh[1][c][o] = v.y;
  }
  __syncthreads();
  int tx = tid & 15, ty = tid >> 4;  // o-quad, ww-quad
  float4 bv = *(const float4*)(up_b + tx * 4);
  float acc[4][4];                   // [a -> ww=ty*4+a][o]
#pragma unroll
  for (int a = 0; a < 4; ++a) {
    acc[a][0] = bv.x; acc[a][1] = bv.y; acc[a][2] = bv.z; acc[a][3] = bv.w;
  }
#pragma unroll 4
  for (int c = 0; c < 128; ++c) {
    float x0 = xs[c][ty * 2];        // ww = 4ty+0,1  (w = 2ty)
    float x1 = xs[c][ty * 2 + 1];    // ww = 4ty+2,3  (w = 2ty+1)
    float4 w0 = *(const float4*)&wsh[0][c][tx * 4];
    float4 w1 = *(const float4*)&wsh[1][c][tx * 4];
    acc[0][0] = fmaf(x0, w0.x, acc[0][0]); acc[0][1] = fmaf(x0, w0.y, acc[0][1]);
    acc[0][2] = fmaf(x0, w0.z, acc[0][2]); acc[0][3] = fmaf(x0, w0.w, acc[0][3]);
    acc[1][0] = fmaf(x0, w1.x, acc[1][0]); acc[1][1] = fmaf(x0, w1.y, acc[1][1]);
    acc[1][2] = fmaf(x0, w1.z, acc[1][2]); acc[1][3] = fmaf(x0, w1.w, acc[1][3]);
    acc[2][0] = fmaf(x1, w0.x, acc[2][0]); acc[2][1] = fmaf(x1, w0.y, acc[2][1]);
    acc[2][2] = fmaf(x1, w0.z, acc[2][2]); acc[2][3] = fmaf(x1, w0.w, acc[2][3]);
    acc[3][0] = fmaf(x1, w1.x, acc[3][0]); acc[3][1] = fmaf(x1, w1.y, acc[3][1]);
    acc[3][2] = fmaf(x1, w1.z, acc[3][2]); acc[3][3] = fmaf(x1, w1.w, acc[3][3]);
  }
  size_t mrow_base = (size_t)b * L_SEQ + (size_t)hh * 64;
#pragma unroll
  for (int a = 0; a < 4; ++a) {
    int ww = ty * 4 + a;
    *(float4*)(seq + (mrow_base + ww) * DM + tx * 4) =
        make_float4(acc[a][0], acc[a][1], acc[a][2], acc[a][3]);
  }
  // skip half: channels 64..127
  for (int e = tid; e < 4096; e += 256) {
    int c = e & 63, ww = e >> 6;
    seq[(mrow_base + ww) * DM + 64 + c] =
        skip[((size_t)b * 64 + c) * (size_t)L_SEQ + hh * 64 + ww];
  }
}

// ---------------- generic fp32 GEMM: C[M][N] = A[M][K] @ W[N][K]^T
__global__ __launch_bounds__(256) void gemm_bt(
    const float* __restrict__ A, const float* __restrict__ W,
    float* __restrict__ C, int M, int N, int K) {
  __shared__ float As[32][68];  // [k][m], pad 68
  __shared__ float Ws[32][68];  // [k][n]
  int m0 = blockIdx.x * 64, n0 = blockIdx.y * 64;
  int tid = threadIdx.x;
  int tx = tid & 15, ty = tid >> 4;
  float acc[4][4];
#pragma unroll
  for (int a = 0; a < 4; ++a)
#pragma unroll
    for (int bb = 0; bb < 4; ++bb) acc[a][bb] = 0.f;

  for (int k0 = 0; k0 < K; k0 += 32) {
    __syncthreads();
    for (int e = tid; e < 512; e += 256) {
      int r = e >> 3;
      int c4 = (e & 7) << 2;
      float4 va = *(const float4*)(A + (size_t)(m0 + r) * K + k0 + c4);
      As[c4 + 0][r] = va.x; As[c4 + 1][r] = va.y;
      As[c4 + 2][r] = va.z; As[c4 + 3][r] = va.w;
      float4 vw = *(const float4*)(W + (size_t)(n0 + r) * K + k0 + c4);
      Ws[c4 + 0][r] = vw.x; Ws[c4 + 1][r] = vw.y;
      Ws[c4 + 2][r] = vw.z; Ws[c4 + 3][r] = vw.w;
    }
    __syncthreads();
#pragma unroll
    for (int kk = 0; kk < 32; ++kk) {
      float4 av = *(const float4*)(&As[kk][ty * 4]);
      float4 wv = *(const float4*)(&Ws[kk][tx * 4]);
      float av_[4] = {av.x, av.y, av.z, av.w};
      float wv_[4] = {wv.x, wv.y, wv.z, wv.w};
#pragma unroll
      for (int a = 0; a < 4; ++a)
#pragma unroll
        for (int bb = 0; bb < 4; ++bb)
          acc[a][bb] = fmaf(av_[a], wv_[bb], acc[a][bb]);
    }
  }
#pragma unroll
  for (int a = 0; a < 4; ++a)
#pragma unroll
    for (int bb = 0; bb < 4; ++bb)
      C[(size_t)(m0 + ty * 4 + a) * N + n0 + tx * 4 + bb] = acc[a][bb];
}

// ---------------- K3: depthwise causal conv1d + bias + silu -> u (B,L,256)
__global__ __launch_bounds__(256) void conv_silu_kernel(
    const float* __restrict__ xz, const float* __restrict__ cw,
    const float* __restrict__ cb, float* __restrict__ u) {
  int idx = blockIdx.x * 256 + threadIdx.x;   // over B*L*256
  int d = idx & 255;
  int m = idx >> 8;
  int l = m & (L_SEQ - 1);
  float acc = cb[d];
#pragma unroll
  for (int t = 0; t < 4; ++t) {
    int ls = l - 3 + t;
    if (ls >= 0)
      acc = fmaf(xz[(size_t)(m - 3 + t) * 512 + d], cw[d * 4 + t], acc);
  }
  u[idx] = acc / (1.f + __expf(-acc));
}

// ---------------- K4a: dbc = u @ x_proj_w^T  (M=16384, N=40, K=256)
__global__ __launch_bounds__(256) void xproj_kernel(
    const float* __restrict__ u, const float* __restrict__ W,
    float* __restrict__ dbc) {
  __shared__ float us[64][68];   // 64 rows x 64-k chunk, pad 68
  int m0 = blockIdx.x * 64;
  int tid = threadIdx.x;
  int lane = tid & 63;
  int w = __builtin_amdgcn_readfirstlane(tid >> 6);  // wave-uniform 0..3
  const float* Wb = W + w * 10 * 256;
  float acc[10];
#pragma unroll
  for (int j = 0; j < 10; ++j) acc[j] = 0.f;
  for (int k0 = 0; k0 < 256; k0 += 64) {
    __syncthreads();
    for (int e = tid; e < 1024; e += 256) {
      int r = e >> 4, q = e & 15;
      float4 v = *(const float4*)(u + (size_t)(m0 + r) * 256 + k0 + q * 4);
      *(float4*)&us[r][q * 4] = v;
    }
    __syncthreads();
#pragma unroll
    for (int kk = 0; kk < 64; kk += 4) {
      float4 a4 = *(const float4*)&us[lane][kk];
      float a_[4] = {a4.x, a4.y, a4.z, a4.w};
#pragma unroll
      for (int i = 0; i < 4; ++i)
#pragma unroll
        for (int j = 0; j < 10; ++j)
          acc[j] = fmaf(a_[i], Wb[j * 256 + k0 + kk + i], acc[j]);
    }
  }
  size_t base = (size_t)(m0 + lane) * 40 + w * 10;
#pragma unroll
  for (int j = 0; j < 10; ++j) dbc[base + j] = acc[j];
}

// ---------------- K5: chunked parallel selective scan ----------------
// thread = (b, chunk, d); 16 n-states in registers. dbc rows staged in LDS
// (broadcast, prefetchable); u/z loaded in-loop (addresses independent of the
// recurrence -> compiler hoists them ahead under unroll-4). No big register
// arrays: R7's ur[32]/zr[32] prefetch spilled (VGPR=256, 41 MB scratch).

__device__ __forceinline__ float softplus_f(float a) {
  return (a > 20.f) ? a : log1pf(__expf(a));
}

__global__ __launch_bounds__(256) void scan_pass1(
    const float* __restrict__ u, const float* __restrict__ dbc,
    const float* __restrict__ A_log, const float* __restrict__ Wdt,
    const float* __restrict__ bdt, float* __restrict__ carryA,
    float* __restrict__ carryH) {
  int bid = blockIdx.x;          // b*NC + c
  int b = bid >> 7;
  int c = bid & (NC - 1);
  int d = threadIdx.x;
  __shared__ float ls[CHUNK * 40];
  size_t l0 = (size_t)b * L_SEQ + (size_t)c * CHUNK;
  const float* rp = dbc + l0 * 40;
  for (int e = d; e < CHUNK * 40; e += 256) ls[e] = rp[e];
  float Ac[16];
  {
    const float4* ar = (const float4*)(A_log + d * 16);
#pragma unroll
    for (int q = 0; q < 4; ++q) {
      float4 v = ar[q];
      Ac[q * 4 + 0] = -__expf(v.x); Ac[q * 4 + 1] = -__expf(v.y);
      Ac[q * 4 + 2] = -__expf(v.z); Ac[q * 4 + 3] = -__expf(v.w);
    }
  }
  float wdt[8];
  {
    const float4* wr = (const float4*)(Wdt + d * 8);
    float4 v0 = wr[0], v1 = wr[1];
    wdt[0] = v0.x; wdt[1] = v0.y; wdt[2] = v0.z; wdt[3] = v0.w;
    wdt[4] = v1.x; wdt[5] = v1.y; wdt[6] = v1.z; wdt[7] = v1.w;
  }
  float bdt_v = bdt[d];
  const float* up = u + l0 * 256 + d;
  __syncthreads();
  float h[16];
#pragma unroll
  for (int n = 0; n < 16; ++n) h[n] = 0.f;
  float dvs = 0.f;
#pragma unroll 4
  for (int li = 0; li < CHUNK; ++li) {
    float uv = up[(size_t)li * 256];
    float acc = bdt_v;
#pragma unroll
    for (int j = 0; j < 8; ++j)
      acc = fmaf(ls[li * 40 + j], wdt[j], acc);
    float dv = softplus_f(acc);
    dvs += dv;
    float t = dv * uv;
#pragma unroll
    for (int n = 0; n < 16; ++n) {
      float dA = __expf(dv * Ac[n]);
      h[n] = fmaf(dA, h[n], t * ls[li * 40 + 8 + n]);
    }
  }
  float4* cA = (float4*)(carryA + ((size_t)bid * 256 + d) * 16);
  float4* cH = (float4*)(carryH + ((size_t)bid * 256 + d) * 16);
#pragma unroll
  for (int q = 0; q < 4; ++q) {
    // prod of dA over chunk == exp(sum(dv) * Ac)
    cA[q] = make_float4(__expf(dvs * Ac[q * 4]), __expf(dvs * Ac[q * 4 + 1]),
                        __expf(dvs * Ac[q * 4 + 2]), __expf(dvs * Ac[q * 4 + 3]));
    cH[q] = make_float4(h[q * 4], h[q * 4 + 1], h[q * 4 + 2], h[q * 4 + 3]);
  }
}

__global__ __launch_bounds__(256) void scan_mid(
    const float* __restrict__ carryA, float* __restrict__ carryH) {
  int gid = blockIdx.x * 256 + threadIdx.x;  // 16384 chains
  int b = gid >> 12;
  int dn = gid & 4095;
  float h = 0.f;
  for (int c = 0; c < NC; ++c) {
    size_t i = ((size_t)(b * NC + c) << 12) + dn;
    float a = carryA[i];
    float hl = carryH[i];
    carryH[i] = h;                 // h entering chunk c
    h = fmaf(a, h, hl);
  }
}

__global__ __launch_bounds__(256) void scan_pass3(
    const float* __restrict__ u, const float* __restrict__ dbc,
    const float* __restrict__ xz, const float* __restrict__ A_log,
    const float* __restrict__ Wdt, const float* __restrict__ bdt,
    const float* __restrict__ Dp, const float* __restrict__ carryH,
    float* __restrict__ y) {
  int bid = blockIdx.x;
  int b = bid >> 7;
  int c = bid & (NC - 1);
  int d = threadIdx.x;
  __shared__ float ls[CHUNK * 40];
  size_t l0 = (size_t)b * L_SEQ + (size_t)c * CHUNK;
  const float* rp = dbc + l0 * 40;
  for (int e = d; e < CHUNK * 40; e += 256) ls[e] = rp[e];
  float Ac[16];
  {
    const float4* ar = (const float4*)(A_log + d * 16);
#pragma unroll
    for (int q = 0; q < 4; ++q) {
      float4 v = ar[q];
      Ac[q * 4 + 0] = -__expf(v.x); Ac[q * 4 + 1] = -__expf(v.y);
      Ac[q * 4 + 2] = -__expf(v.z); Ac[q * 4 + 3] = -__expf(v.w);
    }
  }
  float wdt[8];
  {
    const float4* wr = (const float4*)(Wdt + d * 8);
    float4 v0 = wr[0], v1 = wr[1];
    wdt[0] = v0.x; wdt[1] = v0.y; wdt[2] = v0.z; wdt[3] = v0.w;
    wdt[4] = v1.x; wdt[5] = v1.y; wdt[6] = v1.z; wdt[7] = v1.w;
  }
  float bdt_v = bdt[d];
  float Dv = Dp[d];
  float h[16];
  {
    const float4* cH = (const float4*)(carryH + ((size_t)bid * 256 + d) * 16);
#pragma unroll
    for (int q = 0; q < 4; ++q) {
      float4 v = cH[q];
      h[q * 4 + 0] = v.x; h[q * 4 + 1] = v.y;
      h[q * 4 + 2] = v.z; h[q * 4 + 3] = v.w;
    }
  }
  const float* up = u + l0 * 256 + d;
  const float* zp = xz + l0 * 512 + 256 + d;
  float* yp = y + l0 * 256 + d;
  __syncthreads();
#pragma unroll 4
  for (int li = 0; li < CHUNK; ++li) {
    float uv = up[(size_t)li * 256];
    float zv = zp[(size_t)li * 512];
    float acc = bdt_v;
#pragma unroll
    for (int j = 0; j < 8; ++j)
      acc = fmaf(ls[li * 40 + j], wdt[j], acc);
    float dv = softplus_f(acc);
    float t = dv * uv;
    float p = 0.f;
#pragma unroll
    for (int n = 0; n < 16; ++n) {
      float dA = __expf(dv * Ac[n]);
      h[n] = fmaf(dA, h[n], t * ls[li * 40 + 8 + n]);
      p = fmaf(h[n], ls[li * 40 + 24 + n], p);
    }
    float s = zv / (1.f + __expf(-zv));
    yp[(size_t)li * 256] = (p + uv * Dv) * s;
  }
}

// ---------------- K6: LayerNorm(ch) + silu + 1x1 conv -> out (B,64,H2,W2)
__global__ __launch_bounds__(256) void ln_out_kernel(
    const float* __restrict__ s2, const float* __restrict__ gamma,
    const float* __restrict__ beta, const float* __restrict__ Wo,
    const float* __restrict__ bo, float* __restrict__ out) {
  __shared__ float xt[64][129];
  __shared__ float mus[64], invs[64];
  int tid = threadIdx.x;
  int m0 = blockIdx.x * 64;
  // Phase A: coalesced tile load -> LDS
  for (int i = 0; i < 8; ++i) {
    int s = tid + i * 256;          // 2048 float4 slots
    int r = s >> 5, q = s & 31;
    float4 v = *(const float4*)(s2 + (size_t)(m0 + r) * 128 + q * 4);
    xt[r][q * 4 + 0] = v.x; xt[r][q * 4 + 1] = v.y;
    xt[r][q * 4 + 2] = v.z; xt[r][q * 4 + 3] = v.w;
  }
  __syncthreads();
  // Phase B: stats, 4 threads per row
  {
    int r = tid >> 2, kq = (tid & 3) * 32;
    float s = 0.f, q = 0.f;
#pragma unroll 8
    for (int kk = 0; kk < 32; ++kk) {
      float v = xt[r][kq + kk];
      s += v; q = fmaf(v, v, q);
    }
    s += __shfl_xor(s, 1, 64); s += __shfl_xor(s, 2, 64);
    q += __shfl_xor(q, 1, 64); q += __shfl_xor(q, 2, 64);
    if ((tid & 3) == 0) {
      float mu = s * (1.f / 128.f);
      float var = q * (1.f / 128.f) - mu * mu;
      mus[r] = mu;
      invs[r] = rsqrtf(var + 1e-5f);
    }
  }
  __syncthreads();
  // Phase T: LN + silu in-place
  for (int i = 0; i < 32; ++i) {
    int idx = tid + i * 256;        // 8192 elements
    int r = idx >> 7, k = idx & 127;
    float v = xt[r][k];
    float xn = (v - mus[r]) * invs[r] * gamma[k] + beta[k];
    xt[r][k] = xn / (1.f + __expf(-xn));
  }
  __syncthreads();
  // Phase C: GEMM, lane = row, wave-uniform channels
  int lane = tid & 63;
  int w = __builtin_amdgcn_readfirstlane(tid >> 6);
  int cbase = blockIdx.y * 32 + w * 8;
  const float* Wrow = Wo + cbase * 128;
  float acc[8];
#pragma unroll
  for (int j = 0; j < 8; ++j) acc[j] = 0.f;
#pragma unroll 4
  for (int k = 0; k < 128; ++k) {
    float v = xt[lane][k];
#pragma unroll
    for (int j = 0; j < 8; ++j)
      acc[j] = fmaf(v, Wrow[j * 128 + k], acc[j]);
  }
  int m = m0 + lane;
  int b = m >> 12, l = m & 4095;
#pragma unroll
  for (int j = 0; j < 8; ++j)
    out[((size_t)b * 64 + cbase + j) * 4096 + l] = acc[j] + bo[cbase + j];
}

extern "C" void kernel_launch(void* const* d_in, const int* in_sizes, int n_in,
                              void* d_out, int out_size, void* d_ws, size_t ws_size,
                              hipStream_t stream) {
  (void)in_sizes; (void)n_in; (void)out_size; (void)ws_size;
  const float* x         = (const float*)d_in[0];
  const float* skip      = (const float*)d_in[1];
  const float* up_w      = (const float*)d_in[2];
  const float* up_b      = (const float*)d_in[3];
  const float* in_proj_w = (const float*)d_in[4];
  const float* conv1d_w  = (const float*)d_in[5];
  const float* conv1d_b  = (const float*)d_in[6];
  const float* x_proj_w  = (const float*)d_in[7];
  const float* dt_proj_w = (const float*)d_in[8];
  const float* dt_proj_b = (const float*)d_in[9];
  const float* A_log     = (const float*)d_in[10];
  const float* Dp        = (const float*)d_in[11];
  const float* out_proj_w= (const float*)d_in[12];
  const float* ln_gamma  = (const float*)d_in[13];
  const float* ln_beta   = (const float*)d_in[14];
  const float* convout_w = (const float*)d_in[15];
  const float* convout_b = (const float*)d_in[16];
  float* out = (float*)d_out;
  float* ws  = (float*)d_ws;

  // workspace layout (floats)
  float* seq    = ws;                  // 2,097,152  (reused as s2 after out_proj)
  float* xz     = ws + 2097152;        // 8,388,608
  float* u      = ws + 10485760;       // 4,194,304
  float* dbc    = ws + 14680064;       //   655,360
  float* y      = ws + 15335424;       // 4,194,304
  float* carryA = ws + 19529728;       // 2,097,152  (= 4*NC*256*16)
  float* carryH = ws + 21626880;       // 2,097,152

  upcat_kernel<<<256, 256, 0, stream>>>(x, skip, up_w, up_b, seq);
  gemm_bt<<<dim3(16384 / 64, 512 / 64), 256, 0, stream>>>(seq, in_proj_w, xz,
                                                          16384, 512, 128);
  conv_silu_kernel<<<16384, 256, 0, stream>>>(xz, conv1d_w, conv1d_b, u);
  xproj_kernel<<<16384 / 64, 256, 0, stream>>>(u, x_proj_w, dbc);
  scan_pass1<<<4 * NC, 256, 0, stream>>>(u, dbc, A_log, dt_proj_w, dt_proj_b,
                                         carryA, carryH);
  scan_mid<<<64, 256, 0, stream>>>(carryA, carryH);
  scan_pass3<<<4 * NC, 256, 0, stream>>>(u, dbc, xz, A_log, dt_proj_w,
                                         dt_proj_b, Dp, carryH, y);
  gemm_bt<<<dim3(16384 / 64, 128 / 64), 256, 0, stream>>>(y, out_proj_w, seq,
                                                          16384, 128, 256);
  ln_out_kernel<<<dim3(256, 2), 256, 0, stream>>>(seq, ln_gamma, ln_beta,
                                                  convout_w, convout_b, out);
}

// Round 10
// 204.764 us; speedup vs baseline: 1.2138x; 1.0620x over previous
//
#include <hip/hip_runtime.h>

#define L_SEQ 4096
#define DM 128
#define DIN 256
#define NC 128       // scan chunks
#define CHUNK 32     // L_SEQ / NC

// ---------------- K1: ConvTranspose2d(2x2,s2) + bias + concat -> seq (B,L,128)
__global__ __launch_bounds__(256) void upcat_kernel(
    const float* __restrict__ x, const float* __restrict__ skip,
    const float* __restrict__ up_w, const float* __restrict__ up_b,
    float* __restrict__ seq) {
  int b = blockIdx.x >> 6, hh = blockIdx.x & 63;
  int h = hh >> 1, i = hh & 1;
  int tid = threadIdx.x;
  __shared__ float xs[128][32];      // x[b][c][h][:]
  __shared__ float wsh[2][128][64];  // [j][c][o] for this i
  for (int e = tid; e < 1024; e += 256) {
    int c = e >> 3, q = e & 7;
    *(float4*)&xs[c][q * 4] =
        *(const float4*)(x + (((size_t)b * 128 + c) * 32 + h) * 32 + q * 4);
  }
  for (int e = tid; e < 8192; e += 256) {
    int c = e >> 6, o = e & 63;
    float2 v = *(const float2*)(up_w + c * 256 + o * 4 + i * 2);
    wsh[0][c][o] = v.x;
    wsh[1][c][o] = v.y;
  }
  __syncthreads();
  int tx = tid & 15, ty = tid >> 4;  // o-quad, ww-quad
  float4 bv = *(const float4*)(up_b + tx * 4);
  float acc[4][4];                   // [a -> ww=ty*4+a][o]
#pragma unroll
  for (int a = 0; a < 4; ++a) {
    acc[a][0] = bv.x; acc[a][1] = bv.y; acc[a][2] = bv.z; acc[a][3] = bv.w;
  }
#pragma unroll 4
  for (int c = 0; c < 128; ++c) {
    float x0 = xs[c][ty * 2];        // ww = 4ty+0,1  (w = 2ty)
    float x1 = xs[c][ty * 2 + 1];    // ww = 4ty+2,3  (w = 2ty+1)
    float4 w0 = *(const float4*)&wsh[0][c][tx * 4];
    float4 w1 = *(const float4*)&wsh[1][c][tx * 4];
    acc[0][0] = fmaf(x0, w0.x, acc[0][0]); acc[0][1] = fmaf(x0, w0.y, acc[0][1]);
    acc[0][2] = fmaf(x0, w0.z, acc[0][2]); acc[0][3] = fmaf(x0, w0.w, acc[0][3]);
    acc[1][0] = fmaf(x0, w1.x, acc[1][0]); acc[1][1] = fmaf(x0, w1.y, acc[1][1]);
    acc[1][2] = fmaf(x0, w1.z, acc[1][2]); acc[1][3] = fmaf(x0, w1.w, acc[1][3]);
    acc[2][0] = fmaf(x1, w0.x, acc[2][0]); acc[2][1] = fmaf(x1, w0.y, acc[2][1]);
    acc[2][2] = fmaf(x1, w0.z, acc[2][2]); acc[2][3] = fmaf(x1, w0.w, acc[2][3]);
    acc[3][0] = fmaf(x1, w1.x, acc[3][0]); acc[3][1] = fmaf(x1, w1.y, acc[3][1]);
    acc[3][2] = fmaf(x1, w1.z, acc[3][2]); acc[3][3] = fmaf(x1, w1.w, acc[3][3]);
  }
  size_t mrow_base = (size_t)b * L_SEQ + (size_t)hh * 64;
#pragma unroll
  for (int a = 0; a < 4; ++a) {
    int ww = ty * 4 + a;
    *(float4*)(seq + (mrow_base + ww) * DM + tx * 4) =
        make_float4(acc[a][0], acc[a][1], acc[a][2], acc[a][3]);
  }
  // skip half: channels 64..127
  for (int e = tid; e < 4096; e += 256) {
    int c = e & 63, ww = e >> 6;
    seq[(mrow_base + ww) * DM + 64 + c] =
        skip[((size_t)b * 64 + c) * (size_t)L_SEQ + hh * 64 + ww];
  }
}

// ---------------- generic fp32 GEMM: C[M][N] = A[M][K] @ W[N][K]^T
__global__ __launch_bounds__(256) void gemm_bt(
    const float* __restrict__ A, const float* __restrict__ W,
    float* __restrict__ C, int M, int N, int K) {
  __shared__ float As[32][68];  // [k][m], pad 68
  __shared__ float Ws[32][68];  // [k][n]
  int m0 = blockIdx.x * 64, n0 = blockIdx.y * 64;
  int tid = threadIdx.x;
  int tx = tid & 15, ty = tid >> 4;
  float acc[4][4];
#pragma unroll
  for (int a = 0; a < 4; ++a)
#pragma unroll
    for (int bb = 0; bb < 4; ++bb) acc[a][bb] = 0.f;

  for (int k0 = 0; k0 < K; k0 += 32) {
    __syncthreads();
    for (int e = tid; e < 512; e += 256) {
      int r = e >> 3;
      int c4 = (e & 7) << 2;
      float4 va = *(const float4*)(A + (size_t)(m0 + r) * K + k0 + c4);
      As[c4 + 0][r] = va.x; As[c4 + 1][r] = va.y;
      As[c4 + 2][r] = va.z; As[c4 + 3][r] = va.w;
      float4 vw = *(const float4*)(W + (size_t)(n0 + r) * K + k0 + c4);
      Ws[c4 + 0][r] = vw.x; Ws[c4 + 1][r] = vw.y;
      Ws[c4 + 2][r] = vw.z; Ws[c4 + 3][r] = vw.w;
    }
    __syncthreads();
#pragma unroll
    for (int kk = 0; kk < 32; ++kk) {
      float4 av = *(const float4*)(&As[kk][ty * 4]);
      float4 wv = *(const float4*)(&Ws[kk][tx * 4]);
      float av_[4] = {av.x, av.y, av.z, av.w};
      float wv_[4] = {wv.x, wv.y, wv.z, wv.w};
#pragma unroll
      for (int a = 0; a < 4; ++a)
#pragma unroll
        for (int bb = 0; bb < 4; ++bb)
          acc[a][bb] = fmaf(av_[a], wv_[bb], acc[a][bb]);
    }
  }
#pragma unroll
  for (int a = 0; a < 4; ++a)
#pragma unroll
    for (int bb = 0; bb < 4; ++bb)
      C[(size_t)(m0 + ty * 4 + a) * N + n0 + tx * 4 + bb] = acc[a][bb];
}

// ---------------- K3: depthwise causal conv1d + bias + silu -> u (B,L,256)
__global__ __launch_bounds__(256) void conv_silu_kernel(
    const float* __restrict__ xz, const float* __restrict__ cw,
    const float* __restrict__ cb, float* __restrict__ u) {
  int idx = blockIdx.x * 256 + threadIdx.x;   // over B*L*256
  int d = idx & 255;
  int m = idx >> 8;
  int l = m & (L_SEQ - 1);
  float acc = cb[d];
#pragma unroll
  for (int t = 0; t < 4; ++t) {
    int ls = l - 3 + t;
    if (ls >= 0)
      acc = fmaf(xz[(size_t)(m - 3 + t) * 512 + d], cw[d * 4 + t], acc);
  }
  u[idx] = acc / (1.f + __expf(-acc));
}

// ---------------- K4a: dbc = u @ x_proj_w^T  (M=16384, N=40, K=256)
// grid (M/64, 2); blockIdx.y halves the 40 outputs so each wave owns 5
// (wave-uniform base -> W reads are s_loads) and 2 blocks/CU give the TLP
// needed to hide the mixed ds_read/s_load lgkmcnt drains (ln_out pattern).
__global__ __launch_bounds__(256) void xproj_kernel(
    const float* __restrict__ u, const float* __restrict__ W,
    float* __restrict__ dbc) {
  __shared__ float us[64][68];   // 64 rows x 64-k chunk, pad 68
  int m0 = blockIdx.x * 64;
  int tid = threadIdx.x;
  int lane = tid & 63;
  int w = __builtin_amdgcn_readfirstlane(tid >> 6);  // wave-uniform 0..3
  int jbase = blockIdx.y * 20 + w * 5;
  const float* Wb = W + jbase * 256;
  float acc[5];
#pragma unroll
  for (int j = 0; j < 5; ++j) acc[j] = 0.f;
  for (int k0 = 0; k0 < 256; k0 += 64) {
    __syncthreads();
    for (int e = tid; e < 1024; e += 256) {
      int r = e >> 4, q = e & 15;
      float4 v = *(const float4*)(u + (size_t)(m0 + r) * 256 + k0 + q * 4);
      *(float4*)&us[r][q * 4] = v;
    }
    __syncthreads();
#pragma unroll
    for (int kk = 0; kk < 64; kk += 4) {
      float4 a4 = *(const float4*)&us[lane][kk];
      float a_[4] = {a4.x, a4.y, a4.z, a4.w};
#pragma unroll
      for (int i = 0; i < 4; ++i)
#pragma unroll
        for (int j = 0; j < 5; ++j)
          acc[j] = fmaf(a_[i], Wb[j * 256 + k0 + kk + i], acc[j]);
    }
  }
  size_t base = (size_t)(m0 + lane) * 40 + jbase;
#pragma unroll
  for (int j = 0; j < 5; ++j) dbc[base + j] = acc[j];
}

// ---------------- K5: chunked parallel selective scan ----------------
// thread = (b, chunk, d); 16 n-states in registers. dbc rows staged in LDS
// (broadcast, prefetchable); u/z loaded in-loop (addresses independent of the
// recurrence -> compiler hoists them ahead under unroll-4).

__device__ __forceinline__ float softplus_f(float a) {
  return (a > 20.f) ? a : log1pf(__expf(a));
}

__global__ __launch_bounds__(256) void scan_pass1(
    const float* __restrict__ u, const float* __restrict__ dbc,
    const float* __restrict__ A_log, const float* __restrict__ Wdt,
    const float* __restrict__ bdt, float* __restrict__ carryA,
    float* __restrict__ carryH) {
  int bid = blockIdx.x;          // b*NC + c
  int b = bid >> 7;
  int c = bid & (NC - 1);
  int d = threadIdx.x;
  __shared__ float ls[CHUNK * 40];
  size_t l0 = (size_t)b * L_SEQ + (size_t)c * CHUNK;
  const float* rp = dbc + l0 * 40;
  for (int e = d; e < CHUNK * 40; e += 256) ls[e] = rp[e];
  float Ac[16];
  {
    const float4* ar = (const float4*)(A_log + d * 16);
#pragma unroll
    for (int q = 0; q < 4; ++q) {
      float4 v = ar[q];
      Ac[q * 4 + 0] = -__expf(v.x); Ac[q * 4 + 1] = -__expf(v.y);
      Ac[q * 4 + 2] = -__expf(v.z); Ac[q * 4 + 3] = -__expf(v.w);
    }
  }
  float wdt[8];
  {
    const float4* wr = (const float4*)(Wdt + d * 8);
    float4 v0 = wr[0], v1 = wr[1];
    wdt[0] = v0.x; wdt[1] = v0.y; wdt[2] = v0.z; wdt[3] = v0.w;
    wdt[4] = v1.x; wdt[5] = v1.y; wdt[6] = v1.z; wdt[7] = v1.w;
  }
  float bdt_v = bdt[d];
  const float* up = u + l0 * 256 + d;
  __syncthreads();
  float h[16];
#pragma unroll
  for (int n = 0; n < 16; ++n) h[n] = 0.f;
  float dvs = 0.f;
#pragma unroll 4
  for (int li = 0; li < CHUNK; ++li) {
    float uv = up[(size_t)li * 256];
    float acc = bdt_v;
#pragma unroll
    for (int j = 0; j < 8; ++j)
      acc = fmaf(ls[li * 40 + j], wdt[j], acc);
    float dv = softplus_f(acc);
    dvs += dv;
    float t = dv * uv;
#pragma unroll
    for (int n = 0; n < 16; ++n) {
      float dA = __expf(dv * Ac[n]);
      h[n] = fmaf(dA, h[n], t * ls[li * 40 + 8 + n]);
    }
  }
  float4* cA = (float4*)(carryA + ((size_t)bid * 256 + d) * 16);
  float4* cH = (float4*)(carryH + ((size_t)bid * 256 + d) * 16);
#pragma unroll
  for (int q = 0; q < 4; ++q) {
    // prod of dA over chunk == exp(sum(dv) * Ac)
    cA[q] = make_float4(__expf(dvs * Ac[q * 4]), __expf(dvs * Ac[q * 4 + 1]),
                        __expf(dvs * Ac[q * 4 + 2]), __expf(dvs * Ac[q * 4 + 3]));
    cH[q] = make_float4(h[q * 4], h[q * 4 + 1], h[q * 4 + 2], h[q * 4 + 3]);
  }
}

__global__ __launch_bounds__(256) void scan_mid(
    const float* __restrict__ carryA, float* __restrict__ carryH) {
  int gid = blockIdx.x * 256 + threadIdx.x;  // 16384 chains
  int b = gid >> 12;
  int dn = gid & 4095;
  float h = 0.f;
  for (int c = 0; c < NC; ++c) {
    size_t i = ((size_t)(b * NC + c) << 12) + dn;
    float a = carryA[i];
    float hl = carryH[i];
    carryH[i] = h;                 // h entering chunk c
    h = fmaf(a, h, hl);
  }
}

__global__ __launch_bounds__(256) void scan_pass3(
    const float* __restrict__ u, const float* __restrict__ dbc,
    const float* __restrict__ xz, const float* __restrict__ A_log,
    const float* __restrict__ Wdt, const float* __restrict__ bdt,
    const float* __restrict__ Dp, const float* __restrict__ carryH,
    float* __restrict__ y) {
  int bid = blockIdx.x;
  int b = bid >> 7;
  int c = bid & (NC - 1);
  int d = threadIdx.x;
  __shared__ float ls[CHUNK * 40];
  size_t l0 = (size_t)b * L_SEQ + (size_t)c * CHUNK;
  const float* rp = dbc + l0 * 40;
  for (int e = d; e < CHUNK * 40; e += 256) ls[e] = rp[e];
  float Ac[16];
  {
    const float4* ar = (const float4*)(A_log + d * 16);
#pragma unroll
    for (int q = 0; q < 4; ++q) {
      float4 v = ar[q];
      Ac[q * 4 + 0] = -__expf(v.x); Ac[q * 4 + 1] = -__expf(v.y);
      Ac[q * 4 + 2] = -__expf(v.z); Ac[q * 4 + 3] = -__expf(v.w);
    }
  }
  float wdt[8];
  {
    const float4* wr = (const float4*)(Wdt + d * 8);
    float4 v0 = wr[0], v1 = wr[1];
    wdt[0] = v0.x; wdt[1] = v0.y; wdt[2] = v0.z; wdt[3] = v0.w;
    wdt[4] = v1.x; wdt[5] = v1.y; wdt[6] = v1.z; wdt[7] = v1.w;
  }
  float bdt_v = bdt[d];
  float Dv = Dp[d];
  float h[16];
  {
    const float4* cH = (const float4*)(carryH + ((size_t)bid * 256 + d) * 16);
#pragma unroll
    for (int q = 0; q < 4; ++q) {
      float4 v = cH[q];
      h[q * 4 + 0] = v.x; h[q * 4 + 1] = v.y;
      h[q * 4 + 2] = v.z; h[q * 4 + 3] = v.w;
    }
  }
  const float* up = u + l0 * 256 + d;
  const float* zp = xz + l0 * 512 + 256 + d;
  float* yp = y + l0 * 256 + d;
  __syncthreads();
#pragma unroll 4
  for (int li = 0; li < CHUNK; ++li) {
    float uv = up[(size_t)li * 256];
    float zv = zp[(size_t)li * 512];
    float acc = bdt_v;
#pragma unroll
    for (int j = 0; j < 8; ++j)
      acc = fmaf(ls[li * 40 + j], wdt[j], acc);
    float dv = softplus_f(acc);
    float t = dv * uv;
    float p = 0.f;
#pragma unroll
    for (int n = 0; n < 16; ++n) {
      float dA = __expf(dv * Ac[n]);
      h[n] = fmaf(dA, h[n], t * ls[li * 40 + 8 + n]);
      p = fmaf(h[n], ls[li * 40 + 24 + n], p);
    }
    float s = zv / (1.f + __expf(-zv));
    yp[(size_t)li * 256] = (p + uv * Dv) * s;
  }
}

// ---------------- K6: LayerNorm(ch) + silu + 1x1 conv -> out (B,64,H2,W2)
__global__ __launch_bounds__(256) void ln_out_kernel(
    const float* __restrict__ s2, const float* __restrict__ gamma,
    const float* __restrict__ beta, const float* __restrict__ Wo,
    const float* __restrict__ bo, float* __restrict__ out) {
  __shared__ float xt[64][129];
  __shared__ float mus[64], invs[64];
  int tid = threadIdx.x;
  int m0 = blockIdx.x * 64;
  // Phase A: coalesced tile load -> LDS
  for (int i = 0; i < 8; ++i) {
    int s = tid + i * 256;          // 2048 float4 slots
    int r = s >> 5, q = s & 31;
    float4 v = *(const float4*)(s2 + (size_t)(m0 + r) * 128 + q * 4);
    xt[r][q * 4 + 0] = v.x; xt[r][q * 4 + 1] = v.y;
    xt[r][q * 4 + 2] = v.z; xt[r][q * 4 + 3] = v.w;
  }
  __syncthreads();
  // Phase B: stats, 4 threads per row
  {
    int r = tid >> 2, kq = (tid & 3) * 32;
    float s = 0.f, q = 0.f;
#pragma unroll 8
    for (int kk = 0; kk < 32; ++kk) {
      float v = xt[r][kq + kk];
      s += v; q = fmaf(v, v, q);
    }
    s += __shfl_xor(s, 1, 64); s += __shfl_xor(s, 2, 64);
    q += __shfl_xor(q, 1, 64); q += __shfl_xor(q, 2, 64);
    if ((tid & 3) == 0) {
      float mu = s * (1.f / 128.f);
      float var = q * (1.f / 128.f) - mu * mu;
      mus[r] = mu;
      invs[r] = rsqrtf(var + 1e-5f);
    }
  }
  __syncthreads();
  // Phase T: LN + silu in-place
  for (int i = 0; i < 32; ++i) {
    int idx = tid + i * 256;        // 8192 elements
    int r = idx >> 7, k = idx & 127;
    float v = xt[r][k];
    float xn = (v - mus[r]) * invs[r] * gamma[k] + beta[k];
    xt[r][k] = xn / (1.f + __expf(-xn));
  }
  __syncthreads();
  // Phase C: GEMM, lane = row, wave-uniform channels
  int lane = tid & 63;
  int w = __builtin_amdgcn_readfirstlane(tid >> 6);
  int cbase = blockIdx.y * 32 + w * 8;
  const float* Wrow = Wo + cbase * 128;
  float acc[8];
#pragma unroll
  for (int j = 0; j < 8; ++j) acc[j] = 0.f;
#pragma unroll 4
  for (int k = 0; k < 128; ++k) {
    float v = xt[lane][k];
#pragma unroll
    for (int j = 0; j < 8; ++j)
      acc[j] = fmaf(v, Wrow[j * 128 + k], acc[j]);
  }
  int m = m0 + lane;
  int b = m >> 12, l = m & 4095;
#pragma unroll
  for (int j = 0; j < 8; ++j)
    out[((size_t)b * 64 + cbase + j) * 4096 + l] = acc[j] + bo[cbase + j];
}

extern "C" void kernel_launch(void* const* d_in, const int* in_sizes, int n_in,
                              void* d_out, int out_size, void* d_ws, size_t ws_size,
                              hipStream_t stream) {
  (void)in_sizes; (void)n_in; (void)out_size; (void)ws_size;
  const float* x         = (const float*)d_in[0];
  const float* skip      = (const float*)d_in[1];
  const float* up_w      = (const float*)d_in[2];
  const float* up_b      = (const float*)d_in[3];
  const float* in_proj_w = (const float*)d_in[4];
  const float* conv1d_w  = (const float*)d_in[5];
  const float* conv1d_b  = (const float*)d_in[6];
  const float* x_proj_w  = (const float*)d_in[7];
  const float* dt_proj_w = (const float*)d_in[8];
  const float* dt_proj_b = (const float*)d_in[9];
  const float* A_log     = (const float*)d_in[10];
  const float* Dp        = (const float*)d_in[11];
  const float* out_proj_w= (const float*)d_in[12];
  const float* ln_gamma  = (const float*)d_in[13];
  const float* ln_beta   = (const float*)d_in[14];
  const float* convout_w = (const float*)d_in[15];
  const float* convout_b = (const float*)d_in[16];
  float* out = (float*)d_out;
  float* ws  = (float*)d_ws;

  // workspace layout (floats)
  float* seq    = ws;                  // 2,097,152  (reused as s2 after out_proj)
  float* xz     = ws + 2097152;        // 8,388,608
  float* u      = ws + 10485760;       // 4,194,304
  float* dbc    = ws + 14680064;       //   655,360
  float* y      = ws + 15335424;       // 4,194,304
  float* carryA = ws + 19529728;       // 2,097,152  (= 4*NC*256*16)
  float* carryH = ws + 21626880;       // 2,097,152

  upcat_kernel<<<256, 256, 0, stream>>>(x, skip, up_w, up_b, seq);
  gemm_bt<<<dim3(16384 / 64, 512 / 64), 256, 0, stream>>>(seq, in_proj_w, xz,
                                                          16384, 512, 128);
  conv_silu_kernel<<<16384, 256, 0, stream>>>(xz, conv1d_w, conv1d_b, u);
  xproj_kernel<<<dim3(16384 / 64, 2), 256, 0, stream>>>(u, x_proj_w, dbc);
  scan_pass1<<<4 * NC, 256, 0, stream>>>(u, dbc, A_log, dt_proj_w, dt_proj_b,
                                         carryA, carryH);
  scan_mid<<<64, 256, 0, stream>>>(carryA, carryH);
  scan_pass3<<<4 * NC, 256, 0, stream>>>(u, dbc, xz, A_log, dt_proj_w,
                                         dt_proj_b, Dp, carryH, y);
  gemm_bt<<<dim3(16384 / 64, 128 / 64), 256, 0, stream>>>(y, out_proj_w, seq,
                                                          16384, 128, 256);
  ln_out_kernel<<<dim3(256, 2), 256, 0, stream>>>(seq, ln_gamma, ln_beta,
                                                  convout_w, convout_b, out);
}

// Round 11
// 193.434 us; speedup vs baseline: 1.2849x; 1.0586x over previous
//
#include <hip/hip_runtime.h>

#define L_SEQ 4096
#define DM 128
#define DIN 256
#define NC 128       // scan chunks
#define CHUNK 32     // L_SEQ / NC

// ---------------- K1: ConvTranspose2d(2x2,s2) + bias + concat -> seq (B,L,128)
__global__ __launch_bounds__(256) void upcat_kernel(
    const float* __restrict__ x, const float* __restrict__ skip,
    const float* __restrict__ up_w, const float* __restrict__ up_b,
    float* __restrict__ seq) {
  int b = blockIdx.x >> 6, hh = blockIdx.x & 63;
  int h = hh >> 1, i = hh & 1;
  int tid = threadIdx.x;
  __shared__ float xs[128][32];      // x[b][c][h][:]
  __shared__ float wsh[2][128][64];  // [j][c][o] for this i
  for (int e = tid; e < 1024; e += 256) {
    int c = e >> 3, q = e & 7;
    *(float4*)&xs[c][q * 4] =
        *(const float4*)(x + (((size_t)b * 128 + c) * 32 + h) * 32 + q * 4);
  }
  for (int e = tid; e < 8192; e += 256) {
    int c = e >> 6, o = e & 63;
    float2 v = *(const float2*)(up_w + c * 256 + o * 4 + i * 2);
    wsh[0][c][o] = v.x;
    wsh[1][c][o] = v.y;
  }
  __syncthreads();
  int tx = tid & 15, ty = tid >> 4;  // o-quad, ww-quad
  float4 bv = *(const float4*)(up_b + tx * 4);
  float acc[4][4];                   // [a -> ww=ty*4+a][o]
#pragma unroll
  for (int a = 0; a < 4; ++a) {
    acc[a][0] = bv.x; acc[a][1] = bv.y; acc[a][2] = bv.z; acc[a][3] = bv.w;
  }
#pragma unroll 4
  for (int c = 0; c < 128; ++c) {
    float x0 = xs[c][ty * 2];        // ww = 4ty+0,1  (w = 2ty)
    float x1 = xs[c][ty * 2 + 1];    // ww = 4ty+2,3  (w = 2ty+1)
    float4 w0 = *(const float4*)&wsh[0][c][tx * 4];
    float4 w1 = *(const float4*)&wsh[1][c][tx * 4];
    acc[0][0] = fmaf(x0, w0.x, acc[0][0]); acc[0][1] = fmaf(x0, w0.y, acc[0][1]);
    acc[0][2] = fmaf(x0, w0.z, acc[0][2]); acc[0][3] = fmaf(x0, w0.w, acc[0][3]);
    acc[1][0] = fmaf(x0, w1.x, acc[1][0]); acc[1][1] = fmaf(x0, w1.y, acc[1][1]);
    acc[1][2] = fmaf(x0, w1.z, acc[1][2]); acc[1][3] = fmaf(x0, w1.w, acc[1][3]);
    acc[2][0] = fmaf(x1, w0.x, acc[2][0]); acc[2][1] = fmaf(x1, w0.y, acc[2][1]);
    acc[2][2] = fmaf(x1, w0.z, acc[2][2]); acc[2][3] = fmaf(x1, w0.w, acc[2][3]);
    acc[3][0] = fmaf(x1, w1.x, acc[3][0]); acc[3][1] = fmaf(x1, w1.y, acc[3][1]);
    acc[3][2] = fmaf(x1, w1.z, acc[3][2]); acc[3][3] = fmaf(x1, w1.w, acc[3][3]);
  }
  size_t mrow_base = (size_t)b * L_SEQ + (size_t)hh * 64;
#pragma unroll
  for (int a = 0; a < 4; ++a) {
    int ww = ty * 4 + a;
    *(float4*)(seq + (mrow_base + ww) * DM + tx * 4) =
        make_float4(acc[a][0], acc[a][1], acc[a][2], acc[a][3]);
  }
  // skip half: channels 64..127
  for (int e = tid; e < 4096; e += 256) {
    int c = e & 63, ww = e >> 6;
    seq[(mrow_base + ww) * DM + 64 + c] =
        skip[((size_t)b * 64 + c) * (size_t)L_SEQ + hh * 64 + ww];
  }
}

// ---------------- fp32 GEMM, 128x64 tile, 8x4 acc/thread (in_proj)
__global__ __launch_bounds__(256) void gemm_bt128(
    const float* __restrict__ A, const float* __restrict__ W,
    float* __restrict__ C, int M, int N, int K) {
  __shared__ float As[32][132];  // [k][m], pad 132
  __shared__ float Ws[32][68];   // [k][n], pad 68
  int m0 = blockIdx.x * 128, n0 = blockIdx.y * 64;
  int tid = threadIdx.x;
  int tx = tid & 15, ty = tid >> 4;
  float acc[8][4];
#pragma unroll
  for (int a = 0; a < 8; ++a)
#pragma unroll
    for (int bb = 0; bb < 4; ++bb) acc[a][bb] = 0.f;

  for (int k0 = 0; k0 < K; k0 += 32) {
    __syncthreads();
    for (int e = tid; e < 1024; e += 256) {
      int r = e >> 3, c4 = (e & 7) << 2;
      float4 va = *(const float4*)(A + (size_t)(m0 + r) * K + k0 + c4);
      As[c4 + 0][r] = va.x; As[c4 + 1][r] = va.y;
      As[c4 + 2][r] = va.z; As[c4 + 3][r] = va.w;
    }
    for (int e = tid; e < 512; e += 256) {
      int r = e >> 3, c4 = (e & 7) << 2;
      float4 vw = *(const float4*)(W + (size_t)(n0 + r) * K + k0 + c4);
      Ws[c4 + 0][r] = vw.x; Ws[c4 + 1][r] = vw.y;
      Ws[c4 + 2][r] = vw.z; Ws[c4 + 3][r] = vw.w;
    }
    __syncthreads();
#pragma unroll
    for (int kk = 0; kk < 32; ++kk) {
      float4 a0 = *(const float4*)(&As[kk][ty * 8]);
      float4 a1 = *(const float4*)(&As[kk][ty * 8 + 4]);
      float4 wv = *(const float4*)(&Ws[kk][tx * 4]);
      float a_[8] = {a0.x, a0.y, a0.z, a0.w, a1.x, a1.y, a1.z, a1.w};
      float w_[4] = {wv.x, wv.y, wv.z, wv.w};
#pragma unroll
      for (int a = 0; a < 8; ++a)
#pragma unroll
        for (int bb = 0; bb < 4; ++bb)
          acc[a][bb] = fmaf(a_[a], w_[bb], acc[a][bb]);
    }
  }
#pragma unroll
  for (int a = 0; a < 8; ++a)
#pragma unroll
    for (int bb = 0; bb < 4; ++bb)
      C[(size_t)(m0 + ty * 8 + a) * N + n0 + tx * 4 + bb] = acc[a][bb];
}

// ---------------- generic fp32 GEMM: 64x64 tile (out_proj)
__global__ __launch_bounds__(256) void gemm_bt(
    const float* __restrict__ A, const float* __restrict__ W,
    float* __restrict__ C, int M, int N, int K) {
  __shared__ float As[32][68];  // [k][m], pad 68
  __shared__ float Ws[32][68];  // [k][n]
  int m0 = blockIdx.x * 64, n0 = blockIdx.y * 64;
  int tid = threadIdx.x;
  int tx = tid & 15, ty = tid >> 4;
  float acc[4][4];
#pragma unroll
  for (int a = 0; a < 4; ++a)
#pragma unroll
    for (int bb = 0; bb < 4; ++bb) acc[a][bb] = 0.f;

  for (int k0 = 0; k0 < K; k0 += 32) {
    __syncthreads();
    for (int e = tid; e < 512; e += 256) {
      int r = e >> 3;
      int c4 = (e & 7) << 2;
      float4 va = *(const float4*)(A + (size_t)(m0 + r) * K + k0 + c4);
      As[c4 + 0][r] = va.x; As[c4 + 1][r] = va.y;
      As[c4 + 2][r] = va.z; As[c4 + 3][r] = va.w;
      float4 vw = *(const float4*)(W + (size_t)(n0 + r) * K + k0 + c4);
      Ws[c4 + 0][r] = vw.x; Ws[c4 + 1][r] = vw.y;
      Ws[c4 + 2][r] = vw.z; Ws[c4 + 3][r] = vw.w;
    }
    __syncthreads();
#pragma unroll
    for (int kk = 0; kk < 32; ++kk) {
      float4 av = *(const float4*)(&As[kk][ty * 4]);
      float4 wv = *(const float4*)(&Ws[kk][tx * 4]);
      float av_[4] = {av.x, av.y, av.z, av.w};
      float wv_[4] = {wv.x, wv.y, wv.z, wv.w};
#pragma unroll
      for (int a = 0; a < 4; ++a)
#pragma unroll
        for (int bb = 0; bb < 4; ++bb)
          acc[a][bb] = fmaf(av_[a], wv_[bb], acc[a][bb]);
    }
  }
#pragma unroll
  for (int a = 0; a < 4; ++a)
#pragma unroll
    for (int bb = 0; bb < 4; ++bb)
      C[(size_t)(m0 + ty * 4 + a) * N + n0 + tx * 4 + bb] = acc[a][bb];
}

// ---------------- K4: fused conv1d+silu+xproj: xz -> u (global), dbc
// Stage xz rows m0-3..m0+63 for a 64-d chunk, apply causal 4-tap conv + bias
// + silu in LDS, write u once (y==0), and run the N=40 GEMM off the tile.
// grid (M/64, 2); wave owns 5 outputs (wave-uniform W -> s_loads).
__global__ __launch_bounds__(256) void xproj_kernel(
    const float* __restrict__ xz, const float* __restrict__ cw,
    const float* __restrict__ cb, const float* __restrict__ W,
    float* __restrict__ dbc, float* __restrict__ u_out) {
  __shared__ float xzt[67][64];  // raw xz rows (m0-3+rr)
  __shared__ float us[64][68];   // silu(conv(xz)) = u tile, pad 68
  int m0 = blockIdx.x * 64;
  int tid = threadIdx.x;
  int lane = tid & 63;
  int w = __builtin_amdgcn_readfirstlane(tid >> 6);  // wave-uniform 0..3
  int jbase = blockIdx.y * 20 + w * 5;
  const float* Wb = W + jbase * 256;
  bool first = (m0 & (L_SEQ - 1)) == 0;  // block at sequence start
  int cc4 = (tid & 15) << 2;             // conv-phase column group
  int r0 = tid >> 4;                     // conv-phase row base
  float acc[5];
#pragma unroll
  for (int j = 0; j < 5; ++j) acc[j] = 0.f;
  for (int k0 = 0; k0 < 256; k0 += 64) {
    __syncthreads();
    // stage raw xz (u-half) rows m0-3 .. m0+63 for cols k0..k0+63
    for (int e = tid; e < 67 * 16; e += 256) {
      int rr = e >> 4, c4 = (e & 15) << 2;
      float4 v;
      if (first && rr < 3)
        v = make_float4(0.f, 0.f, 0.f, 0.f);
      else
        v = *(const float4*)(xz + (size_t)(m0 - 3 + rr) * 512 + k0 + c4);
      *(float4*)&xzt[rr][c4] = v;
    }
    __syncthreads();
    // conv + silu -> us (and u global, y==0 only)
    {
      int d = k0 + cc4;
      float4 cw0 = *(const float4*)(cw + (d + 0) * 4);
      float4 cw1 = *(const float4*)(cw + (d + 1) * 4);
      float4 cw2 = *(const float4*)(cw + (d + 2) * 4);
      float4 cw3 = *(const float4*)(cw + (d + 3) * 4);
      float4 cbv = *(const float4*)(cb + d);
#pragma unroll
      for (int s = 0; s < 4; ++s) {
        int r = r0 + s * 16;
        // output row m0+r uses xzt rows r..r+3 (= global m0+r-3 .. m0+r)
        float a0 = cbv.x, a1 = cbv.y, a2 = cbv.z, a3 = cbv.w;
        a0 = fmaf(xzt[r + 0][cc4 + 0], cw0.x, a0);
        a0 = fmaf(xzt[r + 1][cc4 + 0], cw0.y, a0);
        a0 = fmaf(xzt[r + 2][cc4 + 0], cw0.z, a0);
        a0 = fmaf(xzt[r + 3][cc4 + 0], cw0.w, a0);
        a1 = fmaf(xzt[r + 0][cc4 + 1], cw1.x, a1);
        a1 = fmaf(xzt[r + 1][cc4 + 1], cw1.y, a1);
        a1 = fmaf(xzt[r + 2][cc4 + 1], cw1.z, a1);
        a1 = fmaf(xzt[r + 3][cc4 + 1], cw1.w, a1);
        a2 = fmaf(xzt[r + 0][cc4 + 2], cw2.x, a2);
        a2 = fmaf(xzt[r + 1][cc4 + 2], cw2.y, a2);
        a2 = fmaf(xzt[r + 2][cc4 + 2], cw2.z, a2);
        a2 = fmaf(xzt[r + 3][cc4 + 2], cw2.w, a2);
        a3 = fmaf(xzt[r + 0][cc4 + 3], cw3.x, a3);
        a3 = fmaf(xzt[r + 1][cc4 + 3], cw3.y, a3);
        a3 = fmaf(xzt[r + 2][cc4 + 3], cw3.z, a3);
        a3 = fmaf(xzt[r + 3][cc4 + 3], cw3.w, a3);
        float o0 = a0 / (1.f + __expf(-a0));
        float o1 = a1 / (1.f + __expf(-a1));
        float o2 = a2 / (1.f + __expf(-a2));
        float o3 = a3 / (1.f + __expf(-a3));
        *(float4*)&us[r][cc4] = make_float4(o0, o1, o2, o3);
        if (blockIdx.y == 0)
          *(float4*)(u_out + (size_t)(m0 + r) * 256 + d) =
              make_float4(o0, o1, o2, o3);
      }
    }
    __syncthreads();
    // GEMM off the u tile (wave-uniform W reads -> scalar loads)
#pragma unroll
    for (int kk = 0; kk < 64; kk += 4) {
      float4 a4 = *(const float4*)&us[lane][kk];
      float a_[4] = {a4.x, a4.y, a4.z, a4.w};
#pragma unroll
      for (int i = 0; i < 4; ++i)
#pragma unroll
        for (int j = 0; j < 5; ++j)
          acc[j] = fmaf(a_[i], Wb[j * 256 + k0 + kk + i], acc[j]);
    }
  }
  size_t base = (size_t)(m0 + lane) * 40 + jbase;
#pragma unroll
  for (int j = 0; j < 5; ++j) dbc[base + j] = acc[j];
}

// ---------------- K5: chunked parallel selective scan ----------------
__device__ __forceinline__ float softplus_f(float a) {
  return (a > 20.f) ? a : log1pf(__expf(a));
}

__global__ __launch_bounds__(256) void scan_pass1(
    const float* __restrict__ u, const float* __restrict__ dbc,
    const float* __restrict__ A_log, const float* __restrict__ Wdt,
    const float* __restrict__ bdt, float* __restrict__ carryA,
    float* __restrict__ carryH) {
  int bid = blockIdx.x;          // b*NC + c
  int b = bid >> 7;
  int c = bid & (NC - 1);
  int d = threadIdx.x;
  __shared__ float ls[CHUNK * 40];
  size_t l0 = (size_t)b * L_SEQ + (size_t)c * CHUNK;
  const float* rp = dbc + l0 * 40;
  for (int e = d; e < CHUNK * 40; e += 256) ls[e] = rp[e];
  float Ac[16];
  {
    const float4* ar = (const float4*)(A_log + d * 16);
#pragma unroll
    for (int q = 0; q < 4; ++q) {
      float4 v = ar[q];
      Ac[q * 4 + 0] = -__expf(v.x); Ac[q * 4 + 1] = -__expf(v.y);
      Ac[q * 4 + 2] = -__expf(v.z); Ac[q * 4 + 3] = -__expf(v.w);
    }
  }
  float wdt[8];
  {
    const float4* wr = (const float4*)(Wdt + d * 8);
    float4 v0 = wr[0], v1 = wr[1];
    wdt[0] = v0.x; wdt[1] = v0.y; wdt[2] = v0.z; wdt[3] = v0.w;
    wdt[4] = v1.x; wdt[5] = v1.y; wdt[6] = v1.z; wdt[7] = v1.w;
  }
  float bdt_v = bdt[d];
  const float* up = u + l0 * 256 + d;
  __syncthreads();
  float h[16];
#pragma unroll
  for (int n = 0; n < 16; ++n) h[n] = 0.f;
  float dvs = 0.f;
#pragma unroll 4
  for (int li = 0; li < CHUNK; ++li) {
    float uv = up[(size_t)li * 256];
    float acc = bdt_v;
#pragma unroll
    for (int j = 0; j < 8; ++j)
      acc = fmaf(ls[li * 40 + j], wdt[j], acc);
    float dv = softplus_f(acc);
    dvs += dv;
    float t = dv * uv;
#pragma unroll
    for (int n = 0; n < 16; ++n) {
      float dA = __expf(dv * Ac[n]);
      h[n] = fmaf(dA, h[n], t * ls[li * 40 + 8 + n]);
    }
  }
  float4* cA = (float4*)(carryA + ((size_t)bid * 256 + d) * 16);
  float4* cH = (float4*)(carryH + ((size_t)bid * 256 + d) * 16);
#pragma unroll
  for (int q = 0; q < 4; ++q) {
    // prod of dA over chunk == exp(sum(dv) * Ac)
    cA[q] = make_float4(__expf(dvs * Ac[q * 4]), __expf(dvs * Ac[q * 4 + 1]),
                        __expf(dvs * Ac[q * 4 + 2]), __expf(dvs * Ac[q * 4 + 3]));
    cH[q] = make_float4(h[q * 4], h[q * 4 + 1], h[q * 4 + 2], h[q * 4 + 3]);
  }
}

__global__ __launch_bounds__(256) void scan_mid(
    const float* __restrict__ carryA, float* __restrict__ carryH) {
  int gid = blockIdx.x * 256 + threadIdx.x;  // 16384 chains
  int b = gid >> 12;
  int dn = gid & 4095;
  float h = 0.f;
  for (int c = 0; c < NC; ++c) {
    size_t i = ((size_t)(b * NC + c) << 12) + dn;
    float a = carryA[i];
    float hl = carryH[i];
    carryH[i] = h;                 // h entering chunk c
    h = fmaf(a, h, hl);
  }
}

__global__ __launch_bounds__(256) void scan_pass3(
    const float* __restrict__ u, const float* __restrict__ dbc,
    const float* __restrict__ xz, const float* __restrict__ A_log,
    const float* __restrict__ Wdt, const float* __restrict__ bdt,
    const float* __restrict__ Dp, const float* __restrict__ carryH,
    float* __restrict__ y) {
  int bid = blockIdx.x;
  int b = bid >> 7;
  int c = bid & (NC - 1);
  int d = threadIdx.x;
  __shared__ float ls[CHUNK * 40];
  size_t l0 = (size_t)b * L_SEQ + (size_t)c * CHUNK;
  const float* rp = dbc + l0 * 40;
  for (int e = d; e < CHUNK * 40; e += 256) ls[e] = rp[e];
  float Ac[16];
  {
    const float4* ar = (const float4*)(A_log + d * 16);
#pragma unroll
    for (int q = 0; q < 4; ++q) {
      float4 v = ar[q];
      Ac[q * 4 + 0] = -__expf(v.x); Ac[q * 4 + 1] = -__expf(v.y);
      Ac[q * 4 + 2] = -__expf(v.z); Ac[q * 4 + 3] = -__expf(v.w);
    }
  }
  float wdt[8];
  {
    const float4* wr = (const float4*)(Wdt + d * 8);
    float4 v0 = wr[0], v1 = wr[1];
    wdt[0] = v0.x; wdt[1] = v0.y; wdt[2] = v0.z; wdt[3] = v0.w;
    wdt[4] = v1.x; wdt[5] = v1.y; wdt[6] = v1.z; wdt[7] = v1.w;
  }
  float bdt_v = bdt[d];
  float Dv = Dp[d];
  float h[16];
  {
    const float4* cH = (const float4*)(carryH + ((size_t)bid * 256 + d) * 16);
#pragma unroll
    for (int q = 0; q < 4; ++q) {
      float4 v = cH[q];
      h[q * 4 + 0] = v.x; h[q * 4 + 1] = v.y;
      h[q * 4 + 2] = v.z; h[q * 4 + 3] = v.w;
    }
  }
  const float* up = u + l0 * 256 + d;
  const float* zp = xz + l0 * 512 + 256 + d;
  float* yp = y + l0 * 256 + d;
  __syncthreads();
#pragma unroll 4
  for (int li = 0; li < CHUNK; ++li) {
    float uv = up[(size_t)li * 256];
    float zv = zp[(size_t)li * 512];
    float acc = bdt_v;
#pragma unroll
    for (int j = 0; j < 8; ++j)
      acc = fmaf(ls[li * 40 + j], wdt[j], acc);
    float dv = softplus_f(acc);
    float t = dv * uv;
    float p = 0.f;
#pragma unroll
    for (int n = 0; n < 16; ++n) {
      float dA = __expf(dv * Ac[n]);
      h[n] = fmaf(dA, h[n], t * ls[li * 40 + 8 + n]);
      p = fmaf(h[n], ls[li * 40 + 24 + n], p);
    }
    float s = zv / (1.f + __expf(-zv));
    yp[(size_t)li * 256] = (p + uv * Dv) * s;
  }
}

// ---------------- K6: LayerNorm(ch) + silu + 1x1 conv -> out (B,64,H2,W2)
__global__ __launch_bounds__(256) void ln_out_kernel(
    const float* __restrict__ s2, const float* __restrict__ gamma,
    const float* __restrict__ beta, const float* __restrict__ Wo,
    const float* __restrict__ bo, float* __restrict__ out) {
  __shared__ float xt[64][129];
  __shared__ float mus[64], invs[64];
  int tid = threadIdx.x;
  int m0 = blockIdx.x * 64;
  // Phase A: coalesced tile load -> LDS
  for (int i = 0; i < 8; ++i) {
    int s = tid + i * 256;          // 2048 float4 slots
    int r = s >> 5, q = s & 31;
    float4 v = *(const float4*)(s2 + (size_t)(m0 + r) * 128 + q * 4);
    xt[r][q * 4 + 0] = v.x; xt[r][q * 4 + 1] = v.y;
    xt[r][q * 4 + 2] = v.z; xt[r][q * 4 + 3] = v.w;
  }
  __syncthreads();
  // Phase B: stats, 4 threads per row
  {
    int r = tid >> 2, kq = (tid & 3) * 32;
    float s = 0.f, q = 0.f;
#pragma unroll 8
    for (int kk = 0; kk < 32; ++kk) {
      float v = xt[r][kq + kk];
      s += v; q = fmaf(v, v, q);
    }
    s += __shfl_xor(s, 1, 64); s += __shfl_xor(s, 2, 64);
    q += __shfl_xor(q, 1, 64); q += __shfl_xor(q, 2, 64);
    if ((tid & 3) == 0) {
      float mu = s * (1.f / 128.f);
      float var = q * (1.f / 128.f) - mu * mu;
      mus[r] = mu;
      invs[r] = rsqrtf(var + 1e-5f);
    }
  }
  __syncthreads();
  // Phase T: LN + silu in-place
  for (int i = 0; i < 32; ++i) {
    int idx = tid + i * 256;        // 8192 elements
    int r = idx >> 7, k = idx & 127;
    float v = xt[r][k];
    float xn = (v - mus[r]) * invs[r] * gamma[k] + beta[k];
    xt[r][k] = xn / (1.f + __expf(-xn));
  }
  __syncthreads();
  // Phase C: GEMM, lane = row, wave-uniform channels
  int lane = tid & 63;
  int w = __builtin_amdgcn_readfirstlane(tid >> 6);
  int cbase = blockIdx.y * 32 + w * 8;
  const float* Wrow = Wo + cbase * 128;
  float acc[8];
#pragma unroll
  for (int j = 0; j < 8; ++j) acc[j] = 0.f;
#pragma unroll 4
  for (int k = 0; k < 128; ++k) {
    float v = xt[lane][k];
#pragma unroll
    for (int j = 0; j < 8; ++j)
      acc[j] = fmaf(v, Wrow[j * 128 + k], acc[j]);
  }
  int m = m0 + lane;
  int b = m >> 12, l = m & 4095;
#pragma unroll
  for (int j = 0; j < 8; ++j)
    out[((size_t)b * 64 + cbase + j) * 4096 + l] = acc[j] + bo[cbase + j];
}

extern "C" void kernel_launch(void* const* d_in, const int* in_sizes, int n_in,
                              void* d_out, int out_size, void* d_ws, size_t ws_size,
                              hipStream_t stream) {
  (void)in_sizes; (void)n_in; (void)out_size; (void)ws_size;
  const float* x         = (const float*)d_in[0];
  const float* skip      = (const float*)d_in[1];
  const float* up_w      = (const float*)d_in[2];
  const float* up_b      = (const float*)d_in[3];
  const float* in_proj_w = (const float*)d_in[4];
  const float* conv1d_w  = (const float*)d_in[5];
  const float* conv1d_b  = (const float*)d_in[6];
  const float* x_proj_w  = (const float*)d_in[7];
  const float* dt_proj_w = (const float*)d_in[8];
  const float* dt_proj_b = (const float*)d_in[9];
  const float* A_log     = (const float*)d_in[10];
  const float* Dp        = (const float*)d_in[11];
  const float* out_proj_w= (const float*)d_in[12];
  const float* ln_gamma  = (const float*)d_in[13];
  const float* ln_beta   = (const float*)d_in[14];
  const float* convout_w = (const float*)d_in[15];
  const float* convout_b = (const float*)d_in[16];
  float* out = (float*)d_out;
  float* ws  = (float*)d_ws;

  // workspace layout (floats)
  float* seq    = ws;                  // 2,097,152  (reused as s2 after out_proj)
  float* xz     = ws + 2097152;        // 8,388,608
  float* u      = ws + 10485760;       // 4,194,304
  float* dbc    = ws + 14680064;       //   655,360
  float* y      = ws + 15335424;       // 4,194,304
  float* carryA = ws + 19529728;       // 2,097,152  (= 4*NC*256*16)
  float* carryH = ws + 21626880;       // 2,097,152

  upcat_kernel<<<256, 256, 0, stream>>>(x, skip, up_w, up_b, seq);
  gemm_bt128<<<dim3(16384 / 128, 512 / 64), 256, 0, stream>>>(
      seq, in_proj_w, xz, 16384, 512, 128);
  xproj_kernel<<<dim3(16384 / 64, 2), 256, 0, stream>>>(
      xz, conv1d_w, conv1d_b, x_proj_w, dbc, u);
  scan_pass1<<<4 * NC, 256, 0, stream>>>(u, dbc, A_log, dt_proj_w, dt_proj_b,
                                         carryA, carryH);
  scan_mid<<<64, 256, 0, stream>>>(carryA, carryH);
  scan_pass3<<<4 * NC, 256, 0, stream>>>(u, dbc, xz, A_log, dt_proj_w,
                                         dt_proj_b, Dp, carryH, y);
  gemm_bt<<<dim3(16384 / 64, 128 / 64), 256, 0, stream>>>(y, out_proj_w, seq,
                                                          16384, 128, 256);
  ln_out_kernel<<<dim3(256, 2), 256, 0, stream>>>(seq, ln_gamma, ln_beta,
                                                  convout_w, convout_b, out);
}